// Round 9
// baseline (19705.681 us; speedup 1.0000x reference)
//
#include <hip/hip_runtime.h>
#include <math.h>

#define NSYMB  40000
#define NMODES 256
#define LEAD   20000
#define UF     4      // seq prefetch window (step-pairs); 2 chains/lane doubles reg use
#define NM     (NSYMB * NMODES)

// glibc hypotf equivalent: exact double sum, sqrt, single round to f32 (CR)
static __device__ __forceinline__ float crhypotf(float a, float b) {
    const double da = (double)a, db = (double)b;
    return (float)sqrt(da * da + db * db);
}

// Branchless EXACT C-fmodf(xf, f32(pi/2)) WITHOUT an f64 division.
// q = trunc(|x|*ry) is the true quotient or +-1 off; fma(-q,y,|x|) is exact;
// the fixup restores the unique exact remainder in [0,y) -> bits identical
// to the divide-based version.
static __device__ __forceinline__ float fmod_p2_exact(float xf) {
    const double y  = (double)1.57079632679489661923f;
    const double ry = 1.0 / ((double)1.57079632679489661923f);  // CR, compile-time
    const double ax = fabs((double)xf);
    const double q  = __builtin_trunc(ax * ry);
    double r = __builtin_fma(-q, y, ax);                 // exact |x| - q*y, in (-y, 2y)
    r = (r < 0.0) ? (r + y) : ((r >= y) ? (r - y) : r);  // exact fixup -> [0, y)
    return copysignf((float)r, xf);                      // (float)r exact (fmod thm)
}

// Correctly-rounded f32 sincos via bounded-range f64 eval (fdlibm-style),
// BRANCHLESS. |x| < 1e6 always here; 33-bit Cody-Waite pio2_1 keeps
// fma(-fn,pio2_1,x) exact. Quadrant dispatch = cndmask + exact negation.
static __device__ __forceinline__ void cr_sincosf_nb(double x, float& sf, float& cf) {
    const double invpio2 = 6.36619772367581382433e-01;
    const double pio2_1  = 1.57079632673412561417e+00;   // 33 bits of pi/2
    const double pio2_1t = 6.07710050650619224932e-11;   // pi/2 - pio2_1
    const double fn = __builtin_rint(x * invpio2);
    const double rr = __builtin_fma(-fn, pio2_1, x);     // exact
    const double yy = rr - fn * pio2_1t;
    const double z  = yy * yy;
    double ps = __builtin_fma(z, 1.58969099521155010221e-10, -2.50507602534068634195e-08);
    ps = __builtin_fma(z, ps,  2.75573137070700676789e-06);
    ps = __builtin_fma(z, ps, -1.98412698298579493134e-04);
    ps = __builtin_fma(z, ps,  8.33333333332248946124e-03);
    ps = __builtin_fma(z, ps, -1.66666666666666324348e-01);
    const double sv = __builtin_fma(yy * z, ps, yy);
    double pc = __builtin_fma(z, -1.13596475577881948265e-11, 2.08757232129817482790e-09);
    pc = __builtin_fma(z, pc, -2.75573143513906633035e-07);
    pc = __builtin_fma(z, pc,  2.48015872894767294178e-05);
    pc = __builtin_fma(z, pc, -1.38888888888741095749e-03);
    pc = __builtin_fma(z, pc,  4.16666666666666019037e-02);
    const double hz = 0.5 * z;
    const double w1 = 1.0 - hz;
    const double cv = w1 + (((1.0 - w1) - hz) + z * (z * pc)); // fdlibm careful form
    const int n = ((int)fn) & 3;
    const float S = (float)sv, C = (float)cv;
    const bool sw = (n & 1) != 0;
    const float sa = sw ? C : S;                 // n=0:(S,C) 1:(C,-S) 2:(-S,-C) 3:(-C,S)
    const float ca = sw ? S : C;
    sf = (n & 2) ? -sa : sa;
    cf = ((n + 1) & 2) ? -ca : ca;
}

// Rare decision-directed slow path (R5 verbatim): 16-point argmin + jax
// tie-average. noinline keeps ~200 instrs out of the unrolled hot body.
static __device__ __attribute__((noinline)) float2 dd_slow(float zre, float zim) {
#pragma clang fp contract(off)
    const double s10 = sqrt(10.0);
    float Lf[4];
    Lf[0] = (float)(-3.0 / s10); Lf[1] = (float)(-1.0 / s10);
    Lf[2] = (float)( 1.0 / s10); Lf[3] = (float)( 3.0 / s10);
    float dv[16], rv[16], wres[16], wims[16];
    float dmin = __builtin_inff();
#pragma unroll
    for (int k = 0; k < 16; ++k) {
        const float wre = zre - Lf[k >> 2];
        const float wim = zim - Lf[k & 3];
        const float r = crhypotf(wre, wim);
        const float d = r * r;
        wres[k] = wre; wims[k] = wim; rv[k] = r; dv[k] = d;
        dmin = fminf(dmin, d);
    }
    int cnt = 0;
#pragma unroll
    for (int k = 0; k < 16; ++k) cnt += (dv[k] == dmin) ? 1 : 0;
    float A, B;
    if (cnt == 1) {
        int j = 0;
#pragma unroll
        for (int k = 0; k < 16; ++k) if (dv[k] == dmin) j = k;
        A = 2.0f * wres[j];
        B = -(2.0f * wims[j]);
    } else {
        const float ctd = 1.0f / (float)cnt;
        float sa = 0.0f, sb = 0.0f;
#pragma unroll
        for (int k = 0; k < 16; ++k) {
            if (dv[k] == dmin) {
                const float ctr  = (2.0f * rv[k]) * ctd;
                const float ctm2 = ctr / rv[k];
                sa += (ctm2 * wres[k]);
                sb += -(ctm2 * wims[k]);
            }
        }
        A = sa; B = sb;
    }
    return make_float2(A, B);
}

// TWO-CHAIN step: chains A and B are fully independent mode trajectories
// sharing one lane. Source-sequential, arithmetically disjoint -> the block
// scheduler interleaves B's ops into A's dependency bubbles (and vice versa).
// Per-chain op sequence is bit-identical to the single-chain version.
template<bool PILOT>
static __device__ __forceinline__ void pll2_step(
    float yreA, float yimA, float txrA, float txiA,
    float yreB, float yimB, float txrB, float txiB,
    float Kv, const float* Lf, float& phiA, float& phiB)
{
#pragma clang fp contract(off)
    const float QTHf = 0.63245553203367588f;     // bisector 2/sqrt(10)
    float sA, cA, sB, cB;
    cr_sincosf_nb((double)phiA, sA, cA);
    cr_sincosf_nb((double)phiB, sB, cB);
    const float zreA = (yreA * cA) - (yimA * sA);
    const float zimA = (yreA * sA) + (yimA * cA);
    const float zreB = (yreB * cB) - (yimB * sB);
    const float zimB = (yreB * sB) + (yimB * cB);
    float AA, BA, AB, BB;
    if (PILOT) {
        const float wreA = zreA - txrA;
        const float wimA = zimA - txiA;
        AA = 2.0f * wreA;
        BA = -(2.0f * wimA);
        const float wreB = zreB - txrB;
        const float wimB = zimB - txiB;
        AB = 2.0f * wreB;
        BB = -(2.0f * wimB);
    } else {
        // fast path, always computed (bit-equal to literal path off-band, proven)
        const float trA = (zreA < 0.0f) ? ((zreA < -QTHf) ? Lf[0] : Lf[1])
                                        : ((zreA <  QTHf) ? Lf[2] : Lf[3]);
        const float tiA = (zimA < 0.0f) ? ((zimA < -QTHf) ? Lf[0] : Lf[1])
                                        : ((zimA <  QTHf) ? Lf[2] : Lf[3]);
        AA = 2.0f * (zreA - trA);
        BA = -(2.0f * (zimA - tiA));
        const float trB = (zreB < 0.0f) ? ((zreB < -QTHf) ? Lf[0] : Lf[1])
                                        : ((zreB <  QTHf) ? Lf[2] : Lf[3]);
        const float tiB = (zimB < 0.0f) ? ((zimB < -QTHf) ? Lf[0] : Lf[1])
                                        : ((zimB <  QTHf) ? Lf[2] : Lf[3]);
        AB = 2.0f * (zreB - trB);
        BB = -(2.0f * (zimB - tiB));
        const float arA = fabsf(zreA), aiA = fabsf(zimA);
        const float mrA = fminf(fabsf(arA - QTHf), arA);
        const float miA = fminf(fabsf(aiA - QTHf), aiA);
        const bool slowA = !(mrA > 1e-4f && miA > 1e-4f);
        const float arB = fabsf(zreB), aiB = fabsf(zimB);
        const float mrB = fminf(fabsf(arB - QTHf), arB);
        const float miB = fminf(fabsf(aiB - QTHf), aiB);
        const bool slowB = !(mrB > 1e-4f && miB > 1e-4f);
        // one combined rare wave-uniform branch; per-chain guards inside keep
        // per-mode results identical to the single-chain version
        if (__builtin_expect(__ballot(slowA || slowB) != 0ULL, 0)) {
            if (slowA) { const float2 ab = dd_slow(zreA, zimA); AA = ab.x; BA = ab.y; }
            if (slowB) { const float2 ab = dd_slow(zreB, zimB); AB = ab.x; BB = ab.y; }
        }
    }
    // tails (independent, interleavable)
    const float ct_e_reA = (AA * yreA) - (BA * yimA);
    const float ct_e_imA = (AA * yimA) + (BA * yreA);
    const float ct_v_imA = (ct_e_reA * sA) + (ct_e_imA * cA);
    phiA = phiA - (Kv * (-ct_v_imA));
    const float ct_e_reB = (AB * yreB) - (BB * yimB);
    const float ct_e_imB = (AB * yimB) + (BB * yreB);
    const float ct_v_imB = (ct_e_reB * sB) + (ct_e_imB * cB);
    phiB = phiB - (Kv * (-ct_v_imB));
}

// Serial kernel: phi recurrence + raw-phase store, MODE-MAJOR output,
// TWO modes per lane (2 waves total). Each mode's op stream is bit-identical
// to the 1-chain version; co-scheduling fills dependency bubbles.
__global__ __launch_bounds__(64)
void ddpll_seq(const float* __restrict__ ei_re,
               const float* __restrict__ ei_im,
               const float* __restrict__ tx_re,
               const float* __restrict__ tx_im,
               const float* __restrict__ eta,
               float* __restrict__ out)
{
#pragma clang fp contract(off)
    const int mA = blockIdx.x * 64 + threadIdx.x;  // 0..127
    const int mB = mA + 128;                       // 128..255
    const float Kv = (float)tanh((double)eta[0]);  // CR f32 tanh

    const double s10 = sqrt(10.0);
    float Lf[4];
    Lf[0] = (float)(-3.0 / s10); Lf[1] = (float)(-1.0 / s10);
    Lf[2] = (float)( 1.0 / s10); Lf[3] = (float)( 3.0 / s10);

    float phiA = 0.0f, phiB = 0.0f;
    float* __restrict__ thA = out + (size_t)mA * NSYMB;   // mode-major raw th
    float* __restrict__ thB = out + (size_t)mB * NSYMB;

    // ================= phase 1: pilot (t < LEAD) =================
    float ayr[UF], ayi[UF], axr[UF], axi[UF];   // current, chain A
    float byr[UF], byi[UF], bxr[UF], bxi[UF];   // current, chain B
    float Pay[UF], Pai[UF], Par[UF], Pax[UF];   // prefetch, chain A
    float Pby[UF], Pbi[UF], Pbr[UF], Pbx[UF];   // prefetch, chain B
#pragma unroll
    for (int j = 0; j < UF; ++j) {
        const int ia = j * NMODES + mA;
        const int ib = j * NMODES + mB;
        Pay[j] = ei_re[ia]; Pai[j] = ei_im[ia];
        Par[j] = tx_re[ia]; Pax[j] = tx_im[ia];
        Pby[j] = ei_re[ib]; Pbi[j] = ei_im[ib];
        Pbr[j] = tx_re[ib]; Pbx[j] = tx_im[ib];
    }
    for (int tb = 0; tb < LEAD; tb += UF) {
#pragma unroll
        for (int j = 0; j < UF; ++j) {
            ayr[j]=Pay[j]; ayi[j]=Pai[j]; axr[j]=Par[j]; axi[j]=Pax[j];
            byr[j]=Pby[j]; byi[j]=Pbi[j]; bxr[j]=Pbr[j]; bxi[j]=Pbx[j];
        }
        const int nb = tb + UF;
        // branchless prefetch: rows LEAD..LEAD+UF-1 are valid memory
#pragma unroll
        for (int j = 0; j < UF; ++j) {
            const int ia = (nb + j) * NMODES + mA;
            const int ib = (nb + j) * NMODES + mB;
            Pay[j] = ei_re[ia]; Pai[j] = ei_im[ia];
            Par[j] = tx_re[ia]; Pax[j] = tx_im[ia];
            Pby[j] = ei_re[ib]; Pbi[j] = ei_im[ib];
            Pbr[j] = tx_re[ib]; Pbx[j] = tx_im[ib];
        }
#pragma unroll
        for (int j = 0; j < UF; ++j) {
            thA[tb + j] = phiA;                  // raw pre-update phases
            thB[tb + j] = phiB;
            pll2_step<true>(ayr[j], ayi[j], axr[j], axi[j],
                            byr[j], byi[j], bxr[j], bxi[j],
                            Kv, Lf, phiA, phiB);
        }
    }

    // ================= phase 2: decision-directed =================
#pragma unroll
    for (int j = 0; j < UF; ++j) {
        const int ia = (LEAD + j) * NMODES + mA;
        const int ib = (LEAD + j) * NMODES + mB;
        Pay[j] = ei_re[ia]; Pai[j] = ei_im[ia];
        Pby[j] = ei_re[ib]; Pbi[j] = ei_im[ib];
    }
    for (int tb = LEAD; tb < NSYMB; tb += UF) {
#pragma unroll
        for (int j = 0; j < UF; ++j) {
            ayr[j]=Pay[j]; ayi[j]=Pai[j];
            byr[j]=Pby[j]; byi[j]=Pbi[j];
        }
        const int nb = tb + UF;
#pragma unroll
        for (int j = 0; j < UF; ++j) {           // branchless prefetch, clamped
            const int tt = (nb + j < NSYMB) ? (nb + j) : (NSYMB - 1);
            const int ia = tt * NMODES + mA;
            const int ib = tt * NMODES + mB;
            Pay[j] = ei_re[ia]; Pai[j] = ei_im[ia];
            Pby[j] = ei_re[ib]; Pbi[j] = ei_im[ib];
        }
#pragma unroll
        for (int j = 0; j < UF; ++j) {
            thA[tb + j] = phiA;
            thB[tb + j] = phiB;
            pll2_step<false>(ayr[j], ayi[j], 0.0f, 0.0f,
                             byr[j], byi[j], 0.0f, 0.0f,
                             Kv, Lf, phiA, phiB);
        }
    }
}

// Parallel unwrap-correction on the mode-major layout: g = m*NSYMB + t.
// Reads th_T[g], th_T[g-1] (coalesced), writes c_T[g] (coalesced).
// Identical f32/f64 ops as the original in-loop unwrap, on identical th bits.
__global__ __launch_bounds__(256)
void ddpll_unwrapc(const float* __restrict__ thT, float* __restrict__ cT)
{
#pragma clang fp contract(off)
    const float P2f = 1.57079632679489661923f;   // f32(pi/2)
    const float P4f = 0.78539816339744830961f;   // f32(pi/4)
    const int g = blockIdx.x * 256 + threadIdx.x;
    const int m = g / NSYMB;
    const int t = g - m * NSYMB;
    float cv = 0.0f;                              // t==0: no correction
    if (t > 0) {
        const float thv  = thT[g];
        const float prev = thT[g - 1];
        const float dd = thv - prev;
        float rm = fmod_p2_exact(dd + P4f);
        rm = (rm < 0.0f) ? rm + P2f : rm;        // numpy floor-mod
        float ddmod = rm - P4f;
        ddmod = (ddmod == -P4f && dd > 0.0f) ? P4f : ddmod;
        const bool take = !(fabsf(dd) < P4f);
        cv = take ? (ddmod - dd) : 0.0f;
    }
    cT[g] = cv;
}

// Serial scan over mode-major rows: float4 loads (16 in flight), 32 t per
// iteration, stores to the FINAL theta[t][m] layout (lane-coalesced).
// cum fold order identical (adding +0.0f is the identity on cum).
__global__ __launch_bounds__(64)
void ddpll_scan(const float* __restrict__ thT, const float* __restrict__ cT,
                float* __restrict__ theta)
{
#pragma clang fp contract(off)
    const int m = blockIdx.x * 64 + threadIdx.x;   // mode 0..255
    const float4* __restrict__ pth = (const float4*)(thT + (size_t)m * NSYMB);
    const float4* __restrict__ pcv = (const float4*)(cT  + (size_t)m * NSYMB);
    float cum = 0.0f;
    float4 bth[8], bcv[8];
#pragma unroll
    for (int j = 0; j < 8; ++j) { bth[j] = pth[j]; bcv[j] = pcv[j]; }
    for (int tb = 0; tb < NSYMB; tb += 32) {
        float4 th_[8], cv_[8];
#pragma unroll
        for (int j = 0; j < 8; ++j) { th_[j] = bth[j]; cv_[j] = bcv[j]; }
        const int nb4 = (tb + 32) >> 2;            // next block, float4 index
        // unconditional prefetch: final overread (<=32 floats) of the last
        // mode lands in the adjacent c_T/theta regions of the same out buffer
#pragma unroll
        for (int j = 0; j < 8; ++j) { bth[j] = pth[nb4 + j]; bcv[j] = pcv[nb4 + j]; }
#pragma unroll
        for (int j = 0; j < 8; ++j) {
#pragma unroll
            for (int k = 0; k < 4; ++k) {
                const float cc = (&cv_[j].x)[k];
                const float tt = (&th_[j].x)[k];
                cum = cum + cc;                     // == original conditional update
                theta[(tb + j * 4 + k) * NMODES + m] = tt + cum;
            }
        }
    }
}

// Parallel epilogue: Eo = Ei * exp(i * theta_unwrapped)  (err ~1e-6 << thr)
__global__ __launch_bounds__(256)
void ddpll_rot(const float* __restrict__ ei_re,
               const float* __restrict__ ei_im,
               float* __restrict__ out)
{
    const int idx = blockIdx.x * 256 + threadIdx.x;
    const float U = out[(size_t)2 * NM + idx];
    float su, cu;
    sincosf(U, &su, &cu);
    const float yre = ei_re[idx], yim = ei_im[idx];
    out[2 * idx]     = (yre * cu) - (yim * su);
    out[2 * idx + 1] = (yre * su) + (yim * cu);
}

extern "C" void kernel_launch(void* const* d_in, const int* in_sizes, int n_in,
                              void* d_out, int out_size, void* d_ws, size_t ws_size,
                              hipStream_t stream)
{
    (void)in_sizes; (void)n_in; (void)out_size; (void)d_ws; (void)ws_size;
    const float* ei_re = (const float*)d_in[0];
    const float* ei_im = (const float*)d_in[1];
    float* out = (float*)d_out;
    float* thT = out;                 // [0,   NM): mode-major raw phase
    float* cT  = out + (size_t)NM;    // [NM, 2NM): mode-major corrections
    float* th  = out + (size_t)2 * NM;// [2NM,3NM): final theta [t][m]
    // rot overwrites [0,2NM) with Eo only after scan consumed thT/cT.

    ddpll_seq<<<dim3(2), dim3(64), 0, stream>>>(
        ei_re, ei_im,
        (const float*)d_in[2],
        (const float*)d_in[3],
        (const float*)d_in[4],
        out);
    ddpll_unwrapc<<<dim3(NM / 256), dim3(256), 0, stream>>>(thT, cT);
    ddpll_scan<<<dim3(NMODES / 64), dim3(64), 0, stream>>>(thT, cT, th);
    ddpll_rot<<<dim3(NM / 256), dim3(256), 0, stream>>>(ei_re, ei_im, out);
}